// Round 1
// baseline (250.033 us; speedup 1.0000x reference)
//
#include <hip/hip_runtime.h>
#include <cstdint>
#include <cstddef>

typedef int int32x4  __attribute__((ext_vector_type(4)));
typedef int int32x16 __attribute__((ext_vector_type(16)));

#define AS1 __attribute__((address_space(1)))
#define AS3 __attribute__((address_space(3)))

__device__ __forceinline__ void gload_lds16(const void* g, void* l) {
    __builtin_amdgcn_global_load_lds((const AS1 void*)g, (AS3 void*)l, 16, 0, 0);
}

#define MFMA_I8(a, b, c) __builtin_amdgcn_mfma_i32_32x32x32_i8((a), (b), (c), 0, 0, 0)

// ---------------------------------------------------------------------------
// Kernel 1: x (fp32, int8-valued) -> A8 (int8) + row sums rs.
// One block per row. Fully coalesced. ~13us roofline (64MiB read, 16MiB write).
// ---------------------------------------------------------------------------
__global__ __launch_bounds__(256) void quant_x(const float* __restrict__ x,
                                               signed char* __restrict__ A8,
                                               int* __restrict__ rs) {
    const int row = blockIdx.x;
    const int t = threadIdx.x;
    const float4* xr = (const float4*)(x + (size_t)row * 4096);
    char4* ar = (char4*)(A8 + (size_t)row * 4096);
    int s = 0;
#pragma unroll
    for (int i = 0; i < 4; i++) {
        const int idx = i * 256 + t;
        float4 v = xr[idx];
        int a0 = (int)v.x, a1 = (int)v.y, a2 = (int)v.z, a3 = (int)v.w;
        s += a0 + a1 + a2 + a3;
        char4 c;
        c.x = (signed char)a0; c.y = (signed char)a1;
        c.z = (signed char)a2; c.w = (signed char)a3;
        ar[idx] = c;
    }
#pragma unroll
    for (int off = 32; off > 0; off >>= 1) s += __shfl_down(s, off);
    __shared__ int wsum[4];
    if ((t & 63) == 0) wsum[t >> 6] = s;
    __syncthreads();
    if (t == 0) rs[row] = wsum[0] + wsum[1] + wsum[2] + wsum[3];
}

// ---------------------------------------------------------------------------
// Kernel 2 (REWRITTEN): y (fp32, uint8-valued) -> B8T (int8, N-major) + col
// sums sy. Old version did 16 ds_write_b8 per thread (byte-bank hostile).
// New: each thread owns a 4k x 4n micro-tile, packs 4 k-bytes into a dword in
// REGISTERS, transposes via dword LDS (pitch 17 words -> 2 lanes/bank = free
// on both write and read), stores 16B/thread. LDS ops: 4 dword writes +
// 4 dword reads per thread (was 16 byte writes + 4 dword reads).
// ---------------------------------------------------------------------------
__global__ __launch_bounds__(256) void quant_y(const float* __restrict__ y,
                                               signed char* __restrict__ B8T,
                                               int* __restrict__ sy) {
    __shared__ int tile[64 * 17];   // [n][k/4], pitch 17 dwords
    __shared__ int ssum[64];
    const int nt = blockIdx.x * 64;
    const int kt = blockIdx.y * 64;
    const int t = threadIdx.x;
    if (t < 64) ssum[t] = 0;
    __syncthreads();

    const int n4 = (t & 15) * 4;      // 4 n-cols per thread
    const int kb = (t >> 4) * 4;      // 4 k-rows per thread
    int b[4][4];
#pragma unroll
    for (int i = 0; i < 4; i++) {
        float4 v = *(const float4*)(y + (size_t)(kt + kb + i) * 4096 + nt + n4);
        b[i][0] = (int)v.x - 128; b[i][1] = (int)v.y - 128;
        b[i][2] = (int)v.z - 128; b[i][3] = (int)v.w - 128;
    }
#pragma unroll
    for (int j = 0; j < 4; j++) {
        const int s = b[0][j] + b[1][j] + b[2][j] + b[3][j];
        const int w = (b[0][j] & 255) | ((b[1][j] & 255) << 8) |
                      ((b[2][j] & 255) << 16) | (b[3][j] << 24);
        tile[(n4 + j) * 17 + (kb >> 2)] = w;   // pack along k, transpose
        atomicAdd(&ssum[n4 + j], s);
    }
    __syncthreads();

    const int n = t >> 2;             // output row within tile
    const int kq = (t & 3) * 4;       // first dword index of 16B chunk
    int32x4 o;
    o.x = tile[n * 17 + kq + 0];
    o.y = tile[n * 17 + kq + 1];
    o.z = tile[n * 17 + kq + 2];
    o.w = tile[n * 17 + kq + 3];
    *(int32x4*)(B8T + (size_t)(nt + n) * 4096 + kt + kq * 4) = o;
    if (t < 64) atomicAdd(&sy[nt + t], ssum[t]);
}

// ---------------------------------------------------------------------------
// Kernel 3: int8 GEMM, 256(M) x 128(N) tile, BK=64, 4 waves 2x2, wave tile
// 128x64 = 4x2 of 32x32x32 i8 MFMAs. THREE-stage pipeline, raw s_barrier,
// counted vmcnt(6) (proven rounds 1-5).
// NEW this round:
//  (a) T3 fine interleave: K-step split into 4 phases, each
//      {2-4 ds_read_b128 || 1-2 global_load_lds; sched_barrier; s_barrier;
//       setprio(1); 4 MFMA; setprio(0); s_barrier; sched_barrier}.
//      Counted vmcnt only pays inside a per-phase interleave (m196/m218);
//      coarse stage/compute was capping MfmaUtil at 34%.
//  (b) T5 setprio around each MFMA cluster (needs (a)'s role-split).
//  (c) T1 XCD swizzle: lin=(by*32+bx); tile=(lin&7)*64+(lin>>3). 512%8==0 so
//      bijective; each XCD works 2 consecutive tile-rows -> 2 A-panels (2MiB)
//      L2-resident instead of 16 scattered.
// LDS layout unchanged: dense 64B rows, XOR chunk swizzle slot=chunk^((row>>1)&3),
// applied on the GLOBAL source address (global_load_lds dest must be linear).
// Epilogue: C = 7.5e-4 * (P - 32*rs[m] + 66*sy[n] - 8650752)
// ---------------------------------------------------------------------------
__global__ __launch_bounds__(256, 2) void gemm_i8(const signed char* __restrict__ A8,
                                                  const signed char* __restrict__ B8T,
                                                  const int* __restrict__ rs,
                                                  const int* __restrict__ sy,
                                                  float* __restrict__ C) {
    __shared__ __align__(16) signed char As[3 * 16384];  // 256 rows x 64B x 3
    __shared__ __align__(16) signed char Bs[3 * 8192];   // 128 rows x 64B x 3
    const int tid = threadIdx.x;
    const int lin = blockIdx.y * 32 + blockIdx.x;
    const int til = (lin & 7) * 64 + (lin >> 3);   // XCD-contiguous tiles
    const int bm = (til >> 5) * 256;
    const int bn = (til & 31) * 128;
    const int lane = tid & 63;
    const int wave = tid >> 6;
    const int wm = (wave >> 1) * 128;
    const int wn = (wave & 1) * 64;
    const int mr = lane & 31;
    const int kh = lane >> 5;

    int32x16 acc[4][2] = {};

    const int srow = tid >> 2;
    const int scol = ((tid & 3) ^ ((tid >> 3) & 3)) * 16;  // pre-swizzled source
    const size_t arow = (size_t)(bm + srow) * 4096 + scol;
    const size_t brow = (size_t)(bn + srow) * 4096 + scol;

    int aoff[4][2], boff[2][2];
#pragma unroll
    for (int ks = 0; ks < 2; ks++) {
        const int slot = ((ks * 2 + kh) ^ ((mr >> 1) & 3)) * 16;
#pragma unroll
        for (int i = 0; i < 4; i++) aoff[i][ks] = (wm + i * 32 + mr) * 64 + slot;
#pragma unroll
        for (int j = 0; j < 2; j++) boff[j][ks] = (wn + j * 32 + mr) * 64 + slot;
    }

    auto stage = [&](int buf, int kt) {   // prologue only: 6 gloads
        signed char* a_dst = As + buf * 16384 + tid * 16;
        signed char* b_dst = Bs + buf * 8192 + tid * 16;
#pragma unroll
        for (int p = 0; p < 4; p++)
            gload_lds16(A8 + arow + (size_t)p * 262144 + kt, a_dst + p * 4096);
#pragma unroll
        for (int p = 0; p < 2; p++)
            gload_lds16(B8T + brow + (size_t)p * 262144 + kt, b_dst + p * 4096);
    };
    auto compute = [&](int buf) {          // tail only (no pipelining needed)
        const signed char* Ab = As + buf * 16384;
        const signed char* Bb = Bs + buf * 8192;
#pragma unroll
        for (int ks = 0; ks < 2; ks++) {
            int32x4 af[4], bf[2];
#pragma unroll
            for (int i = 0; i < 4; i++) af[i] = *(const int32x4*)(Ab + aoff[i][ks]);
#pragma unroll
            for (int j = 0; j < 2; j++) bf[j] = *(const int32x4*)(Bb + boff[j][ks]);
#pragma unroll
            for (int i = 0; i < 4; i++)
#pragma unroll
                for (int j = 0; j < 2; j++)
                    acc[i][j] = MFMA_I8(af[i], bf[j], acc[i][j]);
        }
    };

    stage(0, 0);
    stage(1, 64);
    // waitcnt imm: vmcnt[3:0]=bits0-3, vmcnt[5:4]=bits14-15, exp=0x70, lgkm=0xF00
    // 0xF76 = vmcnt(6): tile i complete, newest 6 (tile i+1) in flight.
#pragma unroll 1
    for (int kt = 0; kt < 4096 - 64; kt += 64) {
        const int i = kt >> 6;
        const signed char* Ab = As + (i % 3) * 16384;
        const signed char* Bb = Bs + (i % 3) * 8192;
        signed char* a_dst = As + ((i + 2) % 3) * 16384 + tid * 16;
        signed char* b_dst = Bs + ((i + 2) % 3) * 8192 + tid * 16;
        const size_t gka = arow + kt + 128;
        const size_t gkb = brow + kt + 128;
        const bool st = (kt + 128 < 4096);

        __builtin_amdgcn_s_waitcnt(0xF76);
        __builtin_amdgcn_s_barrier();
        __builtin_amdgcn_sched_barrier(0);

        int32x4 a0, a1, b0, b1;
        // ---- phase 0: ks=0, m-rows 0-1; prefetch A halves 0-1 ----
        a0 = *(const int32x4*)(Ab + aoff[0][0]);
        a1 = *(const int32x4*)(Ab + aoff[1][0]);
        b0 = *(const int32x4*)(Bb + boff[0][0]);
        b1 = *(const int32x4*)(Bb + boff[1][0]);
        if (st) {
            gload_lds16(A8 + gka, a_dst);
            gload_lds16(A8 + gka + 262144, a_dst + 4096);
        }
        __builtin_amdgcn_sched_barrier(0);
        __builtin_amdgcn_s_barrier();
        __builtin_amdgcn_s_setprio(1);
        acc[0][0] = MFMA_I8(a0, b0, acc[0][0]);
        acc[0][1] = MFMA_I8(a0, b1, acc[0][1]);
        acc[1][0] = MFMA_I8(a1, b0, acc[1][0]);
        acc[1][1] = MFMA_I8(a1, b1, acc[1][1]);
        __builtin_amdgcn_s_setprio(0);
        __builtin_amdgcn_s_barrier();
        __builtin_amdgcn_sched_barrier(0);
        // ---- phase 1: ks=0, m-rows 2-3; prefetch A halves 2-3 ----
        a0 = *(const int32x4*)(Ab + aoff[2][0]);
        a1 = *(const int32x4*)(Ab + aoff[3][0]);
        if (st) {
            gload_lds16(A8 + gka + 2 * 262144, a_dst + 2 * 4096);
            gload_lds16(A8 + gka + 3 * 262144, a_dst + 3 * 4096);
        }
        __builtin_amdgcn_sched_barrier(0);
        __builtin_amdgcn_s_barrier();
        __builtin_amdgcn_s_setprio(1);
        acc[2][0] = MFMA_I8(a0, b0, acc[2][0]);
        acc[2][1] = MFMA_I8(a0, b1, acc[2][1]);
        acc[3][0] = MFMA_I8(a1, b0, acc[3][0]);
        acc[3][1] = MFMA_I8(a1, b1, acc[3][1]);
        __builtin_amdgcn_s_setprio(0);
        __builtin_amdgcn_s_barrier();
        __builtin_amdgcn_sched_barrier(0);
        // ---- phase 2: ks=1, m-rows 0-1; prefetch B half 0 ----
        a0 = *(const int32x4*)(Ab + aoff[0][1]);
        a1 = *(const int32x4*)(Ab + aoff[1][1]);
        b0 = *(const int32x4*)(Bb + boff[0][1]);
        b1 = *(const int32x4*)(Bb + boff[1][1]);
        if (st) gload_lds16(B8T + gkb, b_dst);
        __builtin_amdgcn_sched_barrier(0);
        __builtin_amdgcn_s_barrier();
        __builtin_amdgcn_s_setprio(1);
        acc[0][0] = MFMA_I8(a0, b0, acc[0][0]);
        acc[0][1] = MFMA_I8(a0, b1, acc[0][1]);
        acc[1][0] = MFMA_I8(a1, b0, acc[1][0]);
        acc[1][1] = MFMA_I8(a1, b1, acc[1][1]);
        __builtin_amdgcn_s_setprio(0);
        __builtin_amdgcn_s_barrier();
        __builtin_amdgcn_sched_barrier(0);
        // ---- phase 3: ks=1, m-rows 2-3; prefetch B half 1 ----
        a0 = *(const int32x4*)(Ab + aoff[2][1]);
        a1 = *(const int32x4*)(Ab + aoff[3][1]);
        if (st) gload_lds16(B8T + gkb + 262144, b_dst + 4096);
        __builtin_amdgcn_sched_barrier(0);
        __builtin_amdgcn_s_barrier();
        __builtin_amdgcn_s_setprio(1);
        acc[2][0] = MFMA_I8(a0, b0, acc[2][0]);
        acc[2][1] = MFMA_I8(a0, b1, acc[2][1]);
        acc[3][0] = MFMA_I8(a1, b0, acc[3][0]);
        acc[3][1] = MFMA_I8(a1, b1, acc[3][1]);
        __builtin_amdgcn_s_setprio(0);
        // no trailing barrier: next iter's vmcnt+barrier paces
    }
    __builtin_amdgcn_s_waitcnt(0xF70);       // vmcnt(0): last tile landed
    __builtin_amdgcn_s_barrier();
    __builtin_amdgcn_sched_barrier(0);
    compute(0);   // tile 63 lives in buf 63%3 == 0

    // Epilogue. C/D: col = lane&31, row = (reg&3) + 8*(reg>>2) + 4*kh
#pragma unroll
    for (int i = 0; i < 4; i++) {
#pragma unroll
        for (int r = 0; r < 16; r++) {
            const int gm = bm + wm + i * 32 + (r & 3) + 8 * (r >> 2) + 4 * kh;
            const int rcorr = -32 * rs[gm] - 8650752;
#pragma unroll
            for (int j = 0; j < 2; j++) {
                const int gn = bn + wn + j * 32 + mr;
                const int v = acc[i][j][r] + rcorr + 66 * sy[gn];
                C[(size_t)gm * 4096 + gn] = 7.5e-4f * (float)v;
            }
        }
    }
}

// ---------------------------------------------------------------------------
extern "C" void kernel_launch(void* const* d_in, const int* in_sizes, int n_in,
                              void* d_out, int out_size, void* d_ws, size_t ws_size,
                              hipStream_t stream) {
    const float* x = (const float*)d_in[0];  // [4096,4096] int8-valued
    const float* y = (const float*)d_in[1];  // [4096,4096] uint8-valued
    float* out = (float*)d_out;

    char* ws = (char*)d_ws;
    signed char* A8  = (signed char*)ws;                         // 16 MiB
    signed char* B8T = (signed char*)(ws + (16u << 20));         // 16 MiB
    int* rs = (int*)(ws + (32u << 20));                          // 16 KiB
    int* sy = (int*)(ws + (32u << 20) + (16u << 10));            // 16 KiB

    hipMemsetAsync(sy, 0, 4096 * sizeof(int), stream);
    quant_x<<<4096, 256, 0, stream>>>(x, A8, rs);
    quant_y<<<dim3(64, 64), 256, 0, stream>>>(y, B8T, sy);
    gemm_i8<<<dim3(32, 16), 256, 0, stream>>>(A8, B8T, rs, sy, out);
}